// Round 6
// baseline (679.026 us; speedup 1.0000x reference)
//
#include <hip/hip_runtime.h>

typedef unsigned short ushort_t;
typedef unsigned int uint_t;

#define SCAN_CHUNK 1024
#define NCH 256          // edge chunks (= pass-A/B grid)
#define BSHIFT 8
#define BNODES 256       // nodes per bucket
#define MAXNB 512        // max buckets (n <= 131072)
#define SLICE_SHIFT 14   // src phase slice = 16384 nodes (2MB bf16 table)
#define MAXP 8           // max phases (n <= 131072)
#define AGG_BLOCKS 1024  // 4 blocks/CU -> exactly co-resident
#define NV 25            // nodes per wave: ceil(100000 / (1024*4))

__device__ __forceinline__ ushort_t f32_to_bf16(float f) {
    uint_t u = __float_as_uint(f);
    return (ushort_t)((u + 0x7FFF + ((u >> 16) & 1)) >> 16);  // RNE
}
__device__ __forceinline__ float bf16_to_f32(ushort_t h) {
    return __uint_as_float((uint_t)h << 16);
}

// ---------------- pass A: per-chunk bucket histogram ----------------

__global__ __launch_bounds__(256) void chunk_hist_kernel(const int* __restrict__ dst,
                                                         int* __restrict__ histG,
                                                         int E, int NB, int chunk) {
    __shared__ int lh[MAXNB];
    int c = blockIdx.x;
    for (int i = threadIdx.x; i < NB; i += 256) lh[i] = 0;
    __syncthreads();
    int beg = c * chunk, end = min(beg + chunk, E);
    int e = beg + threadIdx.x * 4;
    for (; e + 4 <= end; e += 1024) {
        int4 d4 = *reinterpret_cast<const int4*>(&dst[e]);
        atomicAdd(&lh[d4.x >> BSHIFT], 1);
        atomicAdd(&lh[d4.y >> BSHIFT], 1);
        atomicAdd(&lh[d4.z >> BSHIFT], 1);
        atomicAdd(&lh[d4.w >> BSHIFT], 1);
    }
    for (; e < end; ++e) atomicAdd(&lh[dst[e] >> BSHIFT], 1);
    __syncthreads();
    for (int i = threadIdx.x; i < NB; i += 256) histG[i * NCH + c] = lh[i];  // bucket-major
}

// ---------------- 3-kernel exclusive scan of histG (L entries) ----------------

__global__ void block_sum_kernel(const int* __restrict__ in, int* __restrict__ partials, int L) {
    __shared__ int sdata[256];
    int base = blockIdx.x * SCAN_CHUNK;
    int sum = 0;
    for (int i = threadIdx.x; i < SCAN_CHUNK; i += 256) {
        int idx = base + i;
        sum += (idx < L) ? in[idx] : 0;
    }
    sdata[threadIdx.x] = sum;
    __syncthreads();
    for (int s = 128; s > 0; s >>= 1) {
        if (threadIdx.x < s) sdata[threadIdx.x] += sdata[threadIdx.x + s];
        __syncthreads();
    }
    if (threadIdx.x == 0) partials[blockIdx.x] = sdata[0];
}

__global__ void scan_partials_kernel(int* __restrict__ partials, int nb,
                                     int* __restrict__ out, int L) {
    if (threadIdx.x == 0 && blockIdx.x == 0) {
        int acc = 0;
        for (int i = 0; i < nb; i++) { int v = partials[i]; partials[i] = acc; acc += v; }
        out[L] = acc;  // total = E
    }
}

__global__ void scan_write_kernel(const int* __restrict__ in, const int* __restrict__ partials,
                                  int* __restrict__ out, int L) {
    __shared__ int sdata[256];
    int base = blockIdx.x * SCAN_CHUNK;
    int tbase = base + threadIdx.x * 4;
    int vals[4];
    int tsum = 0;
    #pragma unroll
    for (int j = 0; j < 4; j++) {
        int idx = tbase + j;
        vals[j] = (idx < L) ? in[idx] : 0;
        tsum += vals[j];
    }
    sdata[threadIdx.x] = tsum;
    __syncthreads();
    for (int s = 1; s < 256; s <<= 1) {
        int v = (threadIdx.x >= s) ? sdata[threadIdx.x - s] : 0;
        __syncthreads();
        sdata[threadIdx.x] += v;
        __syncthreads();
    }
    int excl = (threadIdx.x == 0) ? 0 : sdata[threadIdx.x - 1];
    int offset = partials[blockIdx.x] + excl;
    #pragma unroll
    for (int j = 0; j < 4; j++) {
        int idx = tbase + j;
        if (idx < L) out[idx] = offset;
        offset += vals[j];
    }
}

// ---------------- pass B: scatter packed (src|ldst<<24) into (bucket,chunk) windows ----------------

__global__ __launch_bounds__(256) void chunk_scatter_kernel(const int* __restrict__ src,
                                                            const int* __restrict__ dst,
                                                            const int* __restrict__ histBase,
                                                            int* __restrict__ binned,
                                                            int E, int NB, int chunk) {
    __shared__ int cur[MAXNB];
    int c = blockIdx.x;
    for (int i = threadIdx.x; i < NB; i += 256) cur[i] = histBase[i * NCH + c];
    __syncthreads();
    int beg = c * chunk, end = min(beg + chunk, E);
    int e = beg + threadIdx.x * 4;
    for (; e + 4 <= end; e += 1024) {
        int4 s4 = *reinterpret_cast<const int4*>(&src[e]);
        int4 d4 = *reinterpret_cast<const int4*>(&dst[e]);
        int p0 = atomicAdd(&cur[d4.x >> BSHIFT], 1);
        binned[p0] = s4.x | ((d4.x & (BNODES - 1)) << 24);
        int p1 = atomicAdd(&cur[d4.y >> BSHIFT], 1);
        binned[p1] = s4.y | ((d4.y & (BNODES - 1)) << 24);
        int p2 = atomicAdd(&cur[d4.z >> BSHIFT], 1);
        binned[p2] = s4.z | ((d4.z & (BNODES - 1)) << 24);
        int p3 = atomicAdd(&cur[d4.w >> BSHIFT], 1);
        binned[p3] = s4.w | ((d4.w & (BNODES - 1)) << 24);
    }
    for (; e < end; ++e) {
        int s = src[e], d = dst[e];
        int pos = atomicAdd(&cur[d >> BSHIFT], 1);
        binned[pos] = s | ((d & (BNODES - 1)) << 24);
    }
}

// ---- fused per-bucket: (node,phase) hist + scan -> row_ptr2/dinv + phase-segmented CSR scatter ----

__global__ __launch_bounds__(256) void bucket_finalize_kernel(const int* __restrict__ binned,
                                                              const int* __restrict__ histBase,
                                                              int* __restrict__ row_ptr2,
                                                              float* __restrict__ dinv,
                                                              int* __restrict__ srcidx,
                                                              int n, int P) {
    __shared__ int cl[BNODES * MAXP];   // (node,phase) counts, then cursors
    __shared__ int sl[BNODES];          // scan workspace
    int b = blockIdx.x;
    int tid = threadIdx.x;
    for (int j = tid; j < BNODES * P; j += 256) cl[j] = 0;
    __syncthreads();
    int beg = histBase[b * NCH], end = histBase[(b + 1) * NCH];
    for (int e = beg + tid; e < end; e += 256) {
        int v = binned[e];
        int s = v & 0xFFFFFF;
        int l = (uint_t)v >> 24;
        atomicAdd(&cl[l * P + (s >> SLICE_SHIFT)], 1);
    }
    __syncthreads();
    int myc[MAXP];
    int mycnt = 0;
    for (int p = 0; p < P; p++) { myc[p] = cl[tid * P + p]; mycnt += myc[p]; }
    sl[tid] = mycnt;
    __syncthreads();
    for (int s = 1; s < 256; s <<= 1) {           // Hillis-Steele inclusive
        int v = (tid >= s) ? sl[tid - s] : 0;
        __syncthreads();
        sl[tid] += v;
        __syncthreads();
    }
    int excl = tid ? sl[tid - 1] : 0;
    int node = (b << BSHIFT) + tid;
    int run = beg + excl;
    for (int p = 0; p < P; p++) {
        cl[tid * P + p] = run;                    // cursor
        if (node < n) row_ptr2[node * P + p] = run;
        run += myc[p];
    }
    if (node < n) {
        dinv[node] = rsqrtf((float)(mycnt + 1));  // +1 self-loop
        if (node == n - 1) row_ptr2[n * P] = run;
    }
    __syncthreads();
    for (int e = beg + tid; e < end; e += 256) {  // bucket slice is L2-hot
        int v = binned[e];
        int s = v & 0xFFFFFF;
        int l = (uint_t)v >> 24;
        int pos = atomicAdd(&cl[l * P + (s >> SLICE_SHIFT)], 1);
        srcidx[pos] = s;
    }
}

// ---------------- dense transform: g[r][c] = bf16(dinv[r] * sum_k in[r][k]*W[k][c]) ----------------

__global__ __launch_bounds__(256) void transform_kernel(const float* __restrict__ in,
                                                        const float* __restrict__ W,
                                                        const float* __restrict__ dinv,
                                                        ushort_t* __restrict__ g, int n) {
    __shared__ float xs[4 * 256];                 // 4 waves/block x (4 rows x 64 floats)
    int lane = threadIdx.x & 63;
    int wslot = threadIdx.x >> 6;
    float* myxs = &xs[wslot * 256];

    float wreg[64];                               // W[k][lane] in VGPRs
    #pragma unroll
    for (int k = 0; k < 64; k++) wreg[k] = W[k * 64 + lane];

    int wave = (blockIdx.x * 256 + threadIdx.x) >> 6;
    int nwaves = gridDim.x * 4;
    int ngroups = (n + 3) >> 2;
    for (int grp = wave; grp < ngroups; grp += nwaves) {
        int r0 = grp * 4;
        if (r0 + 4 <= n) {
            float4 xv = *reinterpret_cast<const float4*>(&in[(size_t)r0 * 64 + lane * 4]);
            *reinterpret_cast<float4*>(&myxs[lane * 4]) = xv;
            float acc0 = 0.f, acc1 = 0.f, acc2 = 0.f, acc3 = 0.f;
            #pragma unroll
            for (int k4 = 0; k4 < 16; k4++) {
                float4 a = *reinterpret_cast<const float4*>(&myxs[0 * 64 + k4 * 4]);
                float4 b = *reinterpret_cast<const float4*>(&myxs[1 * 64 + k4 * 4]);
                float4 c = *reinterpret_cast<const float4*>(&myxs[2 * 64 + k4 * 4]);
                float4 d = *reinterpret_cast<const float4*>(&myxs[3 * 64 + k4 * 4]);
                float w0 = wreg[k4 * 4 + 0], w1 = wreg[k4 * 4 + 1];
                float w2 = wreg[k4 * 4 + 2], w3 = wreg[k4 * 4 + 3];
                acc0 = fmaf(a.x, w0, acc0); acc0 = fmaf(a.y, w1, acc0);
                acc0 = fmaf(a.z, w2, acc0); acc0 = fmaf(a.w, w3, acc0);
                acc1 = fmaf(b.x, w0, acc1); acc1 = fmaf(b.y, w1, acc1);
                acc1 = fmaf(b.z, w2, acc1); acc1 = fmaf(b.w, w3, acc1);
                acc2 = fmaf(c.x, w0, acc2); acc2 = fmaf(c.y, w1, acc2);
                acc2 = fmaf(c.z, w2, acc2); acc2 = fmaf(c.w, w3, acc2);
                acc3 = fmaf(d.x, w0, acc3); acc3 = fmaf(d.y, w1, acc3);
                acc3 = fmaf(d.z, w2, acc3); acc3 = fmaf(d.w, w3, acc3);
            }
            g[(size_t)(r0 + 0) * 64 + lane] = f32_to_bf16(acc0 * dinv[r0 + 0]);
            g[(size_t)(r0 + 1) * 64 + lane] = f32_to_bf16(acc1 * dinv[r0 + 1]);
            g[(size_t)(r0 + 2) * 64 + lane] = f32_to_bf16(acc2 * dinv[r0 + 2]);
            g[(size_t)(r0 + 3) * 64 + lane] = f32_to_bf16(acc3 * dinv[r0 + 3]);
        } else {
            for (int r = r0; r < n; r++) {
                float acc = 0.f;
                #pragma unroll
                for (int k = 0; k < 64; k++) acc = fmaf(in[(size_t)r * 64 + k], wreg[k], acc);
                g[(size_t)r * 64 + lane] = f32_to_bf16(acc * dinv[r]);
            }
        }
    }
}

// ---------------- aggregate: persistent, src-phase-sliced for L2 locality ----------------
// Wave owns NV nodes (acc in registers); all waves sweep src phases in order, so the
// concurrently-accessed slice (2MB) is XCD-L2-resident. No inter-block communication:
// phase loop is a locality heuristic only, correctness is dispatch-order independent.

__global__ __launch_bounds__(256, 4) void aggregate_kernel(const ushort_t* __restrict__ g,
                                                           const int* __restrict__ row_ptr2,
                                                           const int* __restrict__ srcidx,
                                                           const float* __restrict__ dinv,
                                                           const float* __restrict__ bias,
                                                           float* __restrict__ out,
                                                           int n, int P, int relu) {
    int lane = threadIdx.x & 63;
    int wave = (blockIdx.x * 256 + threadIdx.x) >> 6;
    const int NW = AGG_BLOCKS * 4;

    float acc[NV];
    #pragma unroll
    for (int k = 0; k < NV; k++) {
        int node = wave + k * NW;
        acc[k] = (node < n) ? bf16_to_f32(g[(size_t)node * 64 + lane]) : 0.f;  // self term
    }
    for (int p = 0; p < P; p++) {
        #pragma unroll
        for (int k = 0; k < NV; k++) {
            int node = wave + k * NW;
            if (node >= n) continue;
            int e = row_ptr2[node * P + p];
            int e1 = row_ptr2[node * P + p + 1];
            float a = acc[k];
            for (; e + 4 <= e1; e += 4) {
                int s0 = srcidx[e + 0], s1 = srcidx[e + 1];
                int s2 = srcidx[e + 2], s3 = srcidx[e + 3];
                float v0 = bf16_to_f32(g[(size_t)s0 * 64 + lane]);
                float v1 = bf16_to_f32(g[(size_t)s1 * 64 + lane]);
                float v2 = bf16_to_f32(g[(size_t)s2 * 64 + lane]);
                float v3 = bf16_to_f32(g[(size_t)s3 * 64 + lane]);
                a += (v0 + v1) + (v2 + v3);
            }
            for (; e < e1; ++e) a += bf16_to_f32(g[(size_t)srcidx[e] * 64 + lane]);
            acc[k] = a;
        }
    }
    float bl = bias[lane];
    #pragma unroll
    for (int k = 0; k < NV; k++) {
        int node = wave + k * NW;
        if (node >= n) continue;
        float o = fmaf(dinv[node], acc[k], bl);
        out[(size_t)node * 64 + lane] = relu ? fmaxf(o, 0.f) : o;
    }
}

extern "C" void kernel_launch(void* const* d_in, const int* in_sizes, int n_in,
                              void* d_out, int out_size, void* d_ws, size_t ws_size,
                              hipStream_t stream) {
    const float* x  = (const float*)d_in[0];
    const int*   ei = (const int*)d_in[1];
    const float* W1 = (const float*)d_in[2];
    const float* b1 = (const float*)d_in[3];
    const float* W2 = (const float*)d_in[4];
    const float* b2 = (const float*)d_in[5];
    float* out = (float*)d_out;

    const int n = in_sizes[0] / 64;      // 100000
    const int E = in_sizes[1] / 2;       // 3200000
    const int* src = ei;
    const int* dst = ei + E;
    const int NB = (n + BNODES - 1) >> BSHIFT;         // 391 buckets
    const int chunk = (E + NCH - 1) / NCH;             // 12500 edges/chunk
    const int L = NB * NCH;                            // histogram length
    const int P = (n + (1 << SLICE_SHIFT) - 1) >> SLICE_SHIFT;  // 7 phases

    // workspace carve-up (256B aligned)
    char* ws = (char*)d_ws;
    size_t off = 0;
    auto carve = [&](size_t bytes) { char* p = ws + off; off = (off + bytes + 255) & ~(size_t)255; return p; };
    int*      partials = (int*)     carve(4096);
    float*    dinv     = (float*)   carve((size_t)n * 4);
    int*      histG    = (int*)     carve((size_t)L * 4);
    int*      histBase = (int*)     carve((size_t)(L + 1) * 4);
    int*      row_ptr2 = (int*)     carve(((size_t)n * MAXP + 1) * 4);
    int*      srcidx   = (int*)     carve((size_t)E * 4);
    int*      binned   = (int*)     carve((size_t)E * 4);        // packed src|ldst<<24
    ushort_t* g        = (ushort_t*)carve((size_t)n * 64 * 2);   // bf16 scaled features

    const int nbs_hist = (L + SCAN_CHUNK - 1) / SCAN_CHUNK;

    // ---- CSR build via chunked two-pass radix partition (shared by both layers) ----
    chunk_hist_kernel<<<NCH, 256, 0, stream>>>(dst, histG, E, NB, chunk);
    block_sum_kernel<<<nbs_hist, 256, 0, stream>>>(histG, partials, L);
    scan_partials_kernel<<<1, 64, 0, stream>>>(partials, nbs_hist, histBase, L);
    scan_write_kernel<<<nbs_hist, 256, 0, stream>>>(histG, partials, histBase, L);
    chunk_scatter_kernel<<<NCH, 256, 0, stream>>>(src, dst, histBase, binned, E, NB, chunk);
    bucket_finalize_kernel<<<NB, 256, 0, stream>>>(binned, histBase, row_ptr2, dinv, srcidx, n, P);

    // ---- layer 1: g = bf16((x@W1)*dinv) ; h1 = relu(dinv*(agg(g)+g)+b1) -> d_out (f32) ----
    transform_kernel<<<2048, 256, 0, stream>>>(x, W1, dinv, g, n);
    aggregate_kernel<<<AGG_BLOCKS, 256, 0, stream>>>(g, row_ptr2, srcidx, dinv, b1, out, n, P, 1);

    // ---- layer 2: g = bf16((h1@W2)*dinv) ; out = dinv*(agg(g)+g)+b2 ----
    transform_kernel<<<2048, 256, 0, stream>>>(out, W2, dinv, g, n);
    aggregate_kernel<<<AGG_BLOCKS, 256, 0, stream>>>(g, row_ptr2, srcidx, dinv, b2, out, n, P, 0);
}

// Round 7
// 547.142 us; speedup vs baseline: 1.2410x; 1.2410x over previous
//
#include <hip/hip_runtime.h>

typedef unsigned short ushort_t;
typedef unsigned int uint_t;

#define SCAN_CHUNK 1024
#define NCH 256          // edge chunks (= pass-A/B grid)
#define BSHIFT 8
#define BNODES 256       // nodes per bucket
#define MAXNB 512        // max buckets (n <= 131072)

__device__ __forceinline__ ushort_t f32_to_bf16(float f) {
    uint_t u = __float_as_uint(f);
    return (ushort_t)((u + 0x7FFF + ((u >> 16) & 1)) >> 16);  // RNE
}
__device__ __forceinline__ float bf16_to_f32(ushort_t h) {
    return __uint_as_float((uint_t)h << 16);
}

// ---------------- pass A: per-chunk bucket histogram ----------------

__global__ __launch_bounds__(256) void chunk_hist_kernel(const int* __restrict__ dst,
                                                         int* __restrict__ histG,
                                                         int E, int NB, int chunk) {
    __shared__ int lh[MAXNB];
    int c = blockIdx.x;
    for (int i = threadIdx.x; i < NB; i += 256) lh[i] = 0;
    __syncthreads();
    int beg = c * chunk, end = min(beg + chunk, E);
    int e = beg + threadIdx.x * 4;
    for (; e + 4 <= end; e += 1024) {
        int4 d4 = *reinterpret_cast<const int4*>(&dst[e]);
        atomicAdd(&lh[d4.x >> BSHIFT], 1);
        atomicAdd(&lh[d4.y >> BSHIFT], 1);
        atomicAdd(&lh[d4.z >> BSHIFT], 1);
        atomicAdd(&lh[d4.w >> BSHIFT], 1);
    }
    for (; e < end; ++e) atomicAdd(&lh[dst[e] >> BSHIFT], 1);
    __syncthreads();
    for (int i = threadIdx.x; i < NB; i += 256) histG[i * NCH + c] = lh[i];  // bucket-major
}

// ---------------- 3-kernel exclusive scan of histG (L entries) ----------------

__global__ void block_sum_kernel(const int* __restrict__ in, int* __restrict__ partials, int L) {
    __shared__ int sdata[256];
    int base = blockIdx.x * SCAN_CHUNK;
    int sum = 0;
    for (int i = threadIdx.x; i < SCAN_CHUNK; i += 256) {
        int idx = base + i;
        sum += (idx < L) ? in[idx] : 0;
    }
    sdata[threadIdx.x] = sum;
    __syncthreads();
    for (int s = 128; s > 0; s >>= 1) {
        if (threadIdx.x < s) sdata[threadIdx.x] += sdata[threadIdx.x + s];
        __syncthreads();
    }
    if (threadIdx.x == 0) partials[blockIdx.x] = sdata[0];
}

__global__ void scan_partials_kernel(int* __restrict__ partials, int nb,
                                     int* __restrict__ out, int L) {
    if (threadIdx.x == 0 && blockIdx.x == 0) {
        int acc = 0;
        for (int i = 0; i < nb; i++) { int v = partials[i]; partials[i] = acc; acc += v; }
        out[L] = acc;  // total = E
    }
}

__global__ void scan_write_kernel(const int* __restrict__ in, const int* __restrict__ partials,
                                  int* __restrict__ out, int L) {
    __shared__ int sdata[256];
    int base = blockIdx.x * SCAN_CHUNK;
    int tbase = base + threadIdx.x * 4;
    int vals[4];
    int tsum = 0;
    #pragma unroll
    for (int j = 0; j < 4; j++) {
        int idx = tbase + j;
        vals[j] = (idx < L) ? in[idx] : 0;
        tsum += vals[j];
    }
    sdata[threadIdx.x] = tsum;
    __syncthreads();
    for (int s = 1; s < 256; s <<= 1) {
        int v = (threadIdx.x >= s) ? sdata[threadIdx.x - s] : 0;
        __syncthreads();
        sdata[threadIdx.x] += v;
        __syncthreads();
    }
    int excl = (threadIdx.x == 0) ? 0 : sdata[threadIdx.x - 1];
    int offset = partials[blockIdx.x] + excl;
    #pragma unroll
    for (int j = 0; j < 4; j++) {
        int idx = tbase + j;
        if (idx < L) out[idx] = offset;
        offset += vals[j];
    }
}

// ---------------- pass B: scatter packed (src|ldst<<24) into (bucket,chunk) windows ----------------

__global__ __launch_bounds__(256) void chunk_scatter_kernel(const int* __restrict__ src,
                                                            const int* __restrict__ dst,
                                                            const int* __restrict__ histBase,
                                                            int* __restrict__ binned,
                                                            int E, int NB, int chunk) {
    __shared__ int cur[MAXNB];
    int c = blockIdx.x;
    for (int i = threadIdx.x; i < NB; i += 256) cur[i] = histBase[i * NCH + c];
    __syncthreads();
    int beg = c * chunk, end = min(beg + chunk, E);
    int e = beg + threadIdx.x * 4;
    for (; e + 4 <= end; e += 1024) {
        int4 s4 = *reinterpret_cast<const int4*>(&src[e]);
        int4 d4 = *reinterpret_cast<const int4*>(&dst[e]);
        int p0 = atomicAdd(&cur[d4.x >> BSHIFT], 1);
        binned[p0] = s4.x | ((d4.x & (BNODES - 1)) << 24);
        int p1 = atomicAdd(&cur[d4.y >> BSHIFT], 1);
        binned[p1] = s4.y | ((d4.y & (BNODES - 1)) << 24);
        int p2 = atomicAdd(&cur[d4.z >> BSHIFT], 1);
        binned[p2] = s4.z | ((d4.z & (BNODES - 1)) << 24);
        int p3 = atomicAdd(&cur[d4.w >> BSHIFT], 1);
        binned[p3] = s4.w | ((d4.w & (BNODES - 1)) << 24);
    }
    for (; e < end; ++e) {
        int s = src[e], d = dst[e];
        int pos = atomicAdd(&cur[d >> BSHIFT], 1);
        binned[pos] = s | ((d & (BNODES - 1)) << 24);
    }
}

// ---------------- fused per-bucket: node hist + local scan -> row_ptr/dinv + CSR scatter ----------------

__global__ __launch_bounds__(256) void bucket_finalize_kernel(const int* __restrict__ binned,
                                                              const int* __restrict__ histBase,
                                                              int* __restrict__ row_ptr,
                                                              float* __restrict__ dinv,
                                                              int* __restrict__ srcidx, int n) {
    __shared__ int cl[BNODES];   // counts, then cursors
    __shared__ int sl[BNODES];   // scan workspace
    int b = blockIdx.x;
    int tid = threadIdx.x;
    cl[tid] = 0;
    __syncthreads();
    int beg = histBase[b * NCH], end = histBase[(b + 1) * NCH];
    for (int e = beg + tid; e < end; e += 256)
        atomicAdd(&cl[(uint_t)binned[e] >> 24], 1);
    __syncthreads();
    int mycnt = cl[tid];
    sl[tid] = mycnt;
    __syncthreads();
    for (int s = 1; s < 256; s <<= 1) {           // Hillis-Steele inclusive
        int v = (tid >= s) ? sl[tid - s] : 0;
        __syncthreads();
        sl[tid] += v;
        __syncthreads();
    }
    int excl = tid ? sl[tid - 1] : 0;
    int myrp = beg + excl;
    cl[tid] = myrp;                               // becomes fill cursor
    int node = (b << BSHIFT) + tid;
    if (node < n) {
        row_ptr[node] = myrp;
        dinv[node] = rsqrtf((float)(mycnt + 1));  // +1 self-loop
        if (node == n - 1) row_ptr[n] = myrp + mycnt;
    }
    __syncthreads();
    for (int e = beg + tid; e < end; e += 256) {  // binned slice is L2-hot from pass 1
        int v = binned[e];
        int pos = atomicAdd(&cl[(uint_t)v >> 24], 1);
        srcidx[pos] = v & 0xFFFFFF;
    }
}

// ---------------- dense transform: g[r][c] = bf16(dinv[r] * sum_k in[r][k]*W[k][c]) ----------------

__global__ __launch_bounds__(256) void transform_kernel(const float* __restrict__ in,
                                                        const float* __restrict__ W,
                                                        const float* __restrict__ dinv,
                                                        ushort_t* __restrict__ g, int n) {
    __shared__ float xs[4 * 256];                 // 4 waves/block x (4 rows x 64 floats)
    int lane = threadIdx.x & 63;
    int wslot = threadIdx.x >> 6;
    float* myxs = &xs[wslot * 256];

    float wreg[64];                               // W[k][lane] in VGPRs
    #pragma unroll
    for (int k = 0; k < 64; k++) wreg[k] = W[k * 64 + lane];

    int wave = (blockIdx.x * 256 + threadIdx.x) >> 6;
    int nwaves = gridDim.x * 4;
    int ngroups = (n + 3) >> 2;
    for (int grp = wave; grp < ngroups; grp += nwaves) {
        int r0 = grp * 4;
        if (r0 + 4 <= n) {
            float4 xv = *reinterpret_cast<const float4*>(&in[(size_t)r0 * 64 + lane * 4]);
            *reinterpret_cast<float4*>(&myxs[lane * 4]) = xv;
            float acc0 = 0.f, acc1 = 0.f, acc2 = 0.f, acc3 = 0.f;
            #pragma unroll
            for (int k4 = 0; k4 < 16; k4++) {
                float4 a = *reinterpret_cast<const float4*>(&myxs[0 * 64 + k4 * 4]);
                float4 b = *reinterpret_cast<const float4*>(&myxs[1 * 64 + k4 * 4]);
                float4 c = *reinterpret_cast<const float4*>(&myxs[2 * 64 + k4 * 4]);
                float4 d = *reinterpret_cast<const float4*>(&myxs[3 * 64 + k4 * 4]);
                float w0 = wreg[k4 * 4 + 0], w1 = wreg[k4 * 4 + 1];
                float w2 = wreg[k4 * 4 + 2], w3 = wreg[k4 * 4 + 3];
                acc0 = fmaf(a.x, w0, acc0); acc0 = fmaf(a.y, w1, acc0);
                acc0 = fmaf(a.z, w2, acc0); acc0 = fmaf(a.w, w3, acc0);
                acc1 = fmaf(b.x, w0, acc1); acc1 = fmaf(b.y, w1, acc1);
                acc1 = fmaf(b.z, w2, acc1); acc1 = fmaf(b.w, w3, acc1);
                acc2 = fmaf(c.x, w0, acc2); acc2 = fmaf(c.y, w1, acc2);
                acc2 = fmaf(c.z, w2, acc2); acc2 = fmaf(c.w, w3, acc2);
                acc3 = fmaf(d.x, w0, acc3); acc3 = fmaf(d.y, w1, acc3);
                acc3 = fmaf(d.z, w2, acc3); acc3 = fmaf(d.w, w3, acc3);
            }
            g[(size_t)(r0 + 0) * 64 + lane] = f32_to_bf16(acc0 * dinv[r0 + 0]);
            g[(size_t)(r0 + 1) * 64 + lane] = f32_to_bf16(acc1 * dinv[r0 + 1]);
            g[(size_t)(r0 + 2) * 64 + lane] = f32_to_bf16(acc2 * dinv[r0 + 2]);
            g[(size_t)(r0 + 3) * 64 + lane] = f32_to_bf16(acc3 * dinv[r0 + 3]);
        } else {
            for (int r = r0; r < n; r++) {
                float acc = 0.f;
                #pragma unroll
                for (int k = 0; k < 64; k++) acc = fmaf(in[(size_t)r * 64 + k], wreg[k], acc);
                g[(size_t)r * 64 + lane] = f32_to_bf16(acc * dinv[r]);
            }
        }
    }
}

// ---------------- aggregate: feature-quartered, XCD-locked quarter for L2 residency ----------------
// quarter q = (blockIdx%8)>>1: all blocks co-resident on one XCD touch a 16-feature slice
// of g (100000*16*2B = 3.2MB < 4MB L2) -> gathers become L2 hits. Pure locality heuristic;
// correctness independent of block->XCD mapping. Wave: lane = 16*edge_slot + feat.

__global__ __launch_bounds__(256) void aggregate_q_kernel(const ushort_t* __restrict__ g,
                                                          const int* __restrict__ row_ptr,
                                                          const int* __restrict__ srcidx,
                                                          const float* __restrict__ dinv,
                                                          const float* __restrict__ bias,
                                                          float* __restrict__ out,
                                                          int n, int relu) {
    int lane = threadIdx.x & 63;
    int wv = threadIdx.x >> 6;        // 0..3: node slot within block
    int grp = lane >> 4;              // 0..3: edge slot
    int f = lane & 15;                // 0..15: feature within quarter
    int q = (blockIdx.x & 7) >> 1;    // quarter, locked per XCD (blockIdx%8 round-robin)
    int nb = ((blockIdx.x >> 3) << 1) + (blockIdx.x & 1);  // node group 0..ceil(n/4)-1
    int node = nb * 4 + wv;
    if (node >= n) return;
    node = __builtin_amdgcn_readfirstlane(node);
    int col = (q << 4) + f;

    int e0 = row_ptr[node];
    int e1 = row_ptr[node + 1];
    float acc = (grp == 0) ? bf16_to_f32(g[(size_t)node * 64 + col]) : 0.f;  // self term once
    int e = e0;
    for (; e + 16 <= e1; e += 16) {
        int sA = srcidx[e + grp];
        int sB = srcidx[e + 4 + grp];
        int sC = srcidx[e + 8 + grp];
        int sD = srcidx[e + 12 + grp];
        float vA = bf16_to_f32(g[(size_t)sA * 64 + col]);
        float vB = bf16_to_f32(g[(size_t)sB * 64 + col]);
        float vC = bf16_to_f32(g[(size_t)sC * 64 + col]);
        float vD = bf16_to_f32(g[(size_t)sD * 64 + col]);
        acc += (vA + vB) + (vC + vD);
    }
    for (; e + 4 <= e1; e += 4) {
        int s = srcidx[e + grp];
        acc += bf16_to_f32(g[(size_t)s * 64 + col]);
    }
    if (e + grp < e1) {               // remainder 0..3 edges
        int s = srcidx[e + grp];
        acc += bf16_to_f32(g[(size_t)s * 64 + col]);
    }
    // reduce across the 4 edge slots (lane bits 4,5)
    acc += __shfl_xor(acc, 16, 64);
    acc += __shfl_xor(acc, 32, 64);
    if (grp == 0) {
        float o = fmaf(dinv[node], acc, bias[col]);
        out[(size_t)node * 64 + col] = relu ? fmaxf(o, 0.f) : o;
    }
}

extern "C" void kernel_launch(void* const* d_in, const int* in_sizes, int n_in,
                              void* d_out, int out_size, void* d_ws, size_t ws_size,
                              hipStream_t stream) {
    const float* x  = (const float*)d_in[0];
    const int*   ei = (const int*)d_in[1];
    const float* W1 = (const float*)d_in[2];
    const float* b1 = (const float*)d_in[3];
    const float* W2 = (const float*)d_in[4];
    const float* b2 = (const float*)d_in[5];
    float* out = (float*)d_out;

    const int n = in_sizes[0] / 64;      // 100000
    const int E = in_sizes[1] / 2;       // 3200000
    const int* src = ei;
    const int* dst = ei + E;
    const int NB = (n + BNODES - 1) >> BSHIFT;         // 391 buckets
    const int chunk = (E + NCH - 1) / NCH;             // 12500 edges/chunk
    const int L = NB * NCH;                            // histogram length

    // workspace carve-up (256B aligned)
    char* ws = (char*)d_ws;
    size_t off = 0;
    auto carve = [&](size_t bytes) { char* p = ws + off; off = (off + bytes + 255) & ~(size_t)255; return p; };
    int*      row_ptr  = (int*)     carve((size_t)(n + 1) * 4);
    int*      partials = (int*)     carve(4096);
    float*    dinv     = (float*)   carve((size_t)n * 4);
    int*      histG    = (int*)     carve((size_t)L * 4);
    int*      histBase = (int*)     carve((size_t)(L + 1) * 4);
    int*      srcidx   = (int*)     carve((size_t)E * 4);
    int*      binned   = (int*)     carve((size_t)E * 4);        // packed src|ldst<<24
    ushort_t* g        = (ushort_t*)carve((size_t)n * 64 * 2);   // bf16 scaled features

    const int nbs_hist = (L + SCAN_CHUNK - 1) / SCAN_CHUNK;

    // ---- CSR build via chunked two-pass radix partition (shared by both layers) ----
    chunk_hist_kernel<<<NCH, 256, 0, stream>>>(dst, histG, E, NB, chunk);
    block_sum_kernel<<<nbs_hist, 256, 0, stream>>>(histG, partials, L);
    scan_partials_kernel<<<1, 64, 0, stream>>>(partials, nbs_hist, histBase, L);
    scan_write_kernel<<<nbs_hist, 256, 0, stream>>>(histG, partials, histBase, L);
    chunk_scatter_kernel<<<NCH, 256, 0, stream>>>(src, dst, histBase, binned, E, NB, chunk);
    bucket_finalize_kernel<<<NB, 256, 0, stream>>>(binned, histBase, row_ptr, dinv, srcidx, n);

    // aggregate grid: 4 nodes/block, node group nb = (bid>>3)*2 + (bid&1); quarter from bid%8
    const int ngrp4 = (n + 3) / 4;
    const int aggB = ((ngrp4 + 1) / 2) * 8;

    // ---- layer 1: g = bf16((x@W1)*dinv) ; h1 = relu(dinv*(agg(g)+g)+b1) -> d_out (f32) ----
    transform_kernel<<<2048, 256, 0, stream>>>(x, W1, dinv, g, n);
    aggregate_q_kernel<<<aggB, 256, 0, stream>>>(g, row_ptr, srcidx, dinv, b1, out, n, 1);

    // ---- layer 2: g = bf16((h1@W2)*dinv) ; out = dinv*(agg(g)+g)+b2 ----
    transform_kernel<<<2048, 256, 0, stream>>>(out, W2, dinv, g, n);
    aggregate_q_kernel<<<aggB, 256, 0, stream>>>(g, row_ptr, srcidx, dinv, b2, out, n, 0);
}